// Round 1
// baseline (646.995 us; speedup 1.0000x reference)
//
#include <hip/hip_runtime.h>

typedef _Float16 f16;
typedef __attribute__((__ext_vector_type__(8))) _Float16 f16x8;
typedef __attribute__((__ext_vector_type__(4))) float f32x4;

#define GLDS16(g, l) __builtin_amdgcn_global_load_lds( \
    (const __attribute__((address_space(1))) void*)(g), \
    (__attribute__((address_space(3))) void*)(l), 16, 0, 0)

// ---------------- constants ----------------
// x: (16,256,56,56)  w1: (128,256,7,7) dil=2 pad=6 -> k:(16,128,56,56)
// w2: (49,128) -> attn (16,49,56,56); out = sum_ij tap(x) * attn
// P_TOT = 16*56*56 = 50176 positions, padded spatial 68x68.

// ---------------- prep kernels ----------------
__global__ void zero_fill(uint4* __restrict__ p, int n) {
  for (int i = blockIdx.x * blockDim.x + threadIdx.x; i < n;
       i += gridDim.x * blockDim.x)
    p[i] = make_uint4(0u, 0u, 0u, 0u);
}

// x NCHW fp32 -> xpad NHWC fp16, padded 6 on each spatial side (68x68)
__global__ __launch_bounds__(256) void transpose_cast(
    const float* __restrict__ x, f16* __restrict__ xpad) {
  __shared__ float t[256][57];
  const int bh = blockIdx.x;           // b*56 + h
  const int h = bh % 56, b = bh / 56;
  const float* xp = x + (size_t)b * 256 * 3136 + h * 56;
  for (int f = threadIdx.x; f < 256 * 56; f += 256) {
    int c = f / 56, w = f % 56;
    t[c][w] = xp[(size_t)c * 3136 + w];
  }
  __syncthreads();
  f16* op = xpad + (((size_t)(b * 68) + h + 6) * 68 + 6) * 256;
  for (int g = threadIdx.x; g < 56 * 256; g += 256) {
    int w = g / 256, c = g % 256;
    op[(size_t)w * 256 + c] = (f16)t[c][w];
  }
}

// w1 (co,c,i,j) fp32 -> w1h[ij][co][c] fp16
__global__ void w1_transform(const float* __restrict__ w1, f16* __restrict__ w1h) {
  int idx = blockIdx.x * 256 + threadIdx.x;
  if (idx >= 49 * 128 * 256) return;
  int c = idx & 255;
  int rest = idx >> 8;
  int co = rest & 127;
  int ij = rest >> 7;
  w1h[idx] = (f16)w1[((size_t)co * 256 + c) * 49 + ij];
}

// ---------------- conv1 as implicit GEMM (MFMA fp16) ----------------
// M=50176 (positions), N=128 (co), K = 49 taps x 256 ch.
// 128x128 tile, 4 waves each 64x64 (4x4 frags of 16x16x32).
__global__ __launch_bounds__(256, 2) void conv1_gemm(
    const f16* __restrict__ xpad, const f16* __restrict__ w1h,
    const float* __restrict__ b1, float* __restrict__ kbuf) {
  __shared__ f16 Asm[128 * 32];
  __shared__ f16 Bsm[128 * 32];

  const int tid = threadIdx.x;
  const int wid = tid >> 6;
  const int lane = tid & 63;
  const int m0 = blockIdx.x * 128;

  // staging: each wave stages rows [wid*32, wid*32+32) in 2 issues of 16 rows
  const int rq0 = wid * 32 + (lane >> 2);
  const int rq1 = rq0 + 16;
  const int sub = (lane & 3) * 16;  // byte offset within a 64B (32ch) row slice

  auto pos_byte = [&](int r) -> int {
    int P = m0 + r;
    int bb = P / 3136;
    int rem = P - bb * 3136;
    int hh = rem / 56;
    int ww = rem - hh * 56;
    // padded NHWC: [b][hp][wp][256ch], orig (h,w) sits at padded (h+6,w+6);
    // tap (i,j) reads padded (h+2i, w+2j) -> base at (h,w), tap adds offset.
    return ((bb * 68 + hh) * 68 + ww) * 512;
  };
  const int pA0 = pos_byte(rq0) + sub;
  const int pA1 = pos_byte(rq1) + sub;
  const int pB0 = rq0 * 512 + sub;  // w1h row stride 256ch*2B
  const int pB1 = rq1 * 512 + sub;

  const char* xb = (const char*)xpad;
  const char* wb = (const char*)w1h;
  char* As = (char*)Asm;
  char* Bs = (char*)Bsm;
  const int ldsq = wid * 2048;

  const int wr = wid >> 1, wc = wid & 1;
  const int fo = (lane & 15) * 64 + (lane >> 4) * 16;
  const int aoff = wr * 4096 + fo;
  const int boff = wc * 4096 + fo;

  f32x4 acc[4][4] = {};

  for (int ij = 0; ij < 49; ++ij) {
    const int tap = ((ij / 7) * 136 + (ij % 7) * 2) * 512;  // (2i*68+2j)*512B
    const char* ga0 = xb + pA0 + tap;
    const char* ga1 = xb + pA1 + tap;
    const char* gb0 = wb + ij * 65536 + pB0;
    const char* gb1 = wb + ij * 65536 + pB1;
    for (int cc = 0; cc < 8; ++cc) {
      const int cb = cc * 64;  // 32 channels * 2B
      __syncthreads();
      GLDS16(ga0 + cb, As + ldsq);
      GLDS16(ga1 + cb, As + ldsq + 1024);
      GLDS16(gb0 + cb, Bs + ldsq);
      GLDS16(gb1 + cb, Bs + ldsq + 1024);
      __syncthreads();
      f16x8 af[4], bf[4];
#pragma unroll
      for (int m = 0; m < 4; ++m)
        af[m] = *(const f16x8*)(As + aoff + m * 1024);
#pragma unroll
      for (int n = 0; n < 4; ++n)
        bf[n] = *(const f16x8*)(Bs + boff + n * 1024);
#pragma unroll
      for (int m = 0; m < 4; ++m)
#pragma unroll
        for (int n = 0; n < 4; ++n)
          acc[m][n] = __builtin_amdgcn_mfma_f32_16x16x32_f16(
              af[m], bf[n], acc[m][n], 0, 0, 0);
    }
  }

  float bias[4];
#pragma unroll
  for (int n = 0; n < 4; ++n) bias[n] = b1[wc * 64 + n * 16 + (lane & 15)];

#pragma unroll
  for (int m = 0; m < 4; ++m) {
    const int row0 = m0 + wr * 64 + m * 16 + (lane >> 4) * 4;
#pragma unroll
    for (int n = 0; n < 4; ++n) {
      const int co = wc * 64 + n * 16 + (lane & 15);
#pragma unroll
      for (int r = 0; r < 4; ++r) {
        float v = acc[m][n][r] + bias[n];
        kbuf[(size_t)(row0 + r) * 128 + co] = v > 0.f ? v : 0.f;
      }
    }
  }
}

// ---------------- 1x1 conv + BN + relu + softmax(49) ----------------
__global__ __launch_bounds__(256, 1) void conv2_bn_softmax(
    const float* __restrict__ kbuf, const float* __restrict__ w2,
    const float* __restrict__ b2, const float* __restrict__ gamma,
    const float* __restrict__ beta, const float* __restrict__ rmean,
    const float* __restrict__ rvar, float* __restrict__ attn) {
  __shared__ float w2s[49 * 128];
  __shared__ float outs[256 * 49];
  for (int i = threadIdx.x; i < 49 * 128; i += 256) w2s[i] = w2[i];
  __syncthreads();
  const int p = blockIdx.x * 256 + threadIdx.x;
  float acc[49];
#pragma unroll
  for (int o = 0; o < 49; ++o) acc[o] = 0.f;
  const float4* kp = (const float4*)(kbuf + (size_t)p * 128);
  for (int c4 = 0; c4 < 32; ++c4) {
    float4 kv = kp[c4];
#pragma unroll
    for (int o = 0; o < 49; ++o) {
      float4 wv = *(const float4*)(w2s + o * 128 + c4 * 4);
      acc[o] += kv.x * wv.x + kv.y * wv.y + kv.z * wv.z + kv.w * wv.w;
    }
  }
  float mx = -1e30f;
#pragma unroll
  for (int o = 0; o < 49; ++o) {
    float s = acc[o] + b2[o];
    float inv = gamma[o] * rsqrtf(rvar[o] + 1e-5f);
    s = (s - rmean[o]) * inv + beta[o];
    s = s > 0.f ? s : 0.f;
    acc[o] = s;
    mx = fmaxf(mx, s);
  }
  float sum = 0.f;
#pragma unroll
  for (int o = 0; o < 49; ++o) {
    float e = __expf(acc[o] - mx);
    acc[o] = e;
    sum += e;
  }
  const float rinv = 1.f / sum;
  float* orow = outs + threadIdx.x * 49;
#pragma unroll
  for (int o = 0; o < 49; ++o) orow[o] = acc[o] * rinv;
  __syncthreads();
  float* ab = attn + (size_t)blockIdx.x * (256 * 49);
  for (int i = threadIdx.x; i < 256 * 49; i += 256) ab[i] = outs[i];
}

// ---------------- attention-weighted aggregation ----------------
// block: (b, h, c-chunk of 32); stages 7 x-rows (padded to 68) per channel
// and the attn row for all 56 w.
__global__ __launch_bounds__(256, 2) void aggregate(
    const float* __restrict__ x, const float* __restrict__ attn,
    float* __restrict__ out) {
  __shared__ float xs[32][7][68];  // 60928 B
  __shared__ float as[56 * 49];    // 10976 B
  const int bid = blockIdx.x;      // ((b*56+h)*8 + cchunk)
  const int cchunk = bid & 7;
  const int bh = bid >> 3;
  const int h = bh % 56, b = bh / 56;
  const int c0 = cchunk * 32;

  const float* ap = attn + (size_t)(b * 56 + h) * 56 * 49;
  for (int i = threadIdx.x; i < 56 * 49; i += 256) as[i] = ap[i];
  for (int idx = threadIdx.x; idx < 32 * 7 * 68; idx += 256) {
    int wp = idx % 68;
    int rest = idx / 68;
    int i = rest % 7;
    int c = rest / 7;
    int hsrc = h + 2 * i - 6;
    int wsrc = wp - 6;
    float v = 0.f;
    if (hsrc >= 0 && hsrc < 56 && wsrc >= 0 && wsrc < 56)
      v = x[((size_t)(b * 256 + c0 + c) * 56 + hsrc) * 56 + wsrc];
    xs[c][i][wp] = v;
  }
  __syncthreads();
  for (int o = threadIdx.x; o < 32 * 56; o += 256) {
    int w = o % 56, c = o / 56;
    float acc = 0.f;
    const float* arow = as + w * 49;
#pragma unroll
    for (int i = 0; i < 7; ++i)
#pragma unroll
      for (int j = 0; j < 7; ++j)
        acc += arow[i * 7 + j] * xs[c][i][w + 2 * j];
    out[((size_t)(b * 256 + c0 + c) * 56 + h) * 56 + w] = acc;
  }
}

// ---------------- launch ----------------
extern "C" void kernel_launch(void* const* d_in, const int* in_sizes, int n_in,
                              void* d_out, int out_size, void* d_ws,
                              size_t ws_size, hipStream_t stream) {
  const float* x = (const float*)d_in[0];
  const float* w1 = (const float*)d_in[1];
  const float* b1 = (const float*)d_in[2];
  const float* w2 = (const float*)d_in[3];
  const float* b2 = (const float*)d_in[4];
  const float* gamma = (const float*)d_in[5];
  const float* beta = (const float*)d_in[6];
  const float* rmean = (const float*)d_in[7];
  const float* rvar = (const float*)d_in[8];
  float* out = (float*)d_out;

  char* ws = (char*)d_ws;
  f16* xpad = (f16*)ws;                      // 16*68*68*256*2 = 37,879,808 B
  f16* w1h = (f16*)(ws + 37879808);          // 49*128*256*2  =  3,211,264 B
  float* kbuf = (float*)(ws + 41091072);     // 50176*128*4   = 25,690,112 B
  float* attn = (float*)(ws + 66781184);     // 50176*49*4    =  9,834,496 B

  hipLaunchKernelGGL(zero_fill, dim3(2048), dim3(256), 0, stream, (uint4*)xpad,
                     2367488);
  hipLaunchKernelGGL(transpose_cast, dim3(896), dim3(256), 0, stream, x, xpad);
  hipLaunchKernelGGL(w1_transform, dim3(6272), dim3(256), 0, stream, w1, w1h);
  hipLaunchKernelGGL(conv1_gemm, dim3(392), dim3(256), 0, stream, xpad, w1h,
                     b1, kbuf);
  hipLaunchKernelGGL(conv2_bn_softmax, dim3(196), dim3(256), 0, stream, kbuf,
                     w2, b2, gamma, beta, rmean, rvar, attn);
  hipLaunchKernelGGL(aggregate, dim3(7168), dim3(256), 0, stream, x, attn, out);
}

// Round 2
// 380.626 us; speedup vs baseline: 1.6998x; 1.6998x over previous
//
#include <hip/hip_runtime.h>

typedef _Float16 f16;
typedef __attribute__((__ext_vector_type__(4))) _Float16 f16x4;
typedef __attribute__((__ext_vector_type__(8))) _Float16 f16x8;
typedef __attribute__((__ext_vector_type__(4))) float f32x4;

#define GLDS16(g, l) __builtin_amdgcn_global_load_lds( \
    (const __attribute__((address_space(1))) void*)(g), \
    (__attribute__((address_space(3))) void*)(l), 16, 0, 0)

// ---------------- constants ----------------
// x: (16,256,56,56)  w1: (128,256,7,7) dil=2 pad=6 -> k:(16,128,56,56)
// w2: (49,128) -> attn (16,49,56,56); out = sum_ij tap(x) * attn
// P_TOT = 16*56*56 = 50176 positions, padded spatial 68x68.

// ---------------- prep kernels ----------------
__global__ void zero_fill(uint4* __restrict__ p, int n) {
  for (int i = blockIdx.x * blockDim.x + threadIdx.x; i < n;
       i += gridDim.x * blockDim.x)
    p[i] = make_uint4(0u, 0u, 0u, 0u);
}

// x NCHW fp32 -> xpad NHWC fp16, padded 6 on each spatial side (68x68)
__global__ __launch_bounds__(256) void transpose_cast(
    const float* __restrict__ x, f16* __restrict__ xpad) {
  __shared__ float t[256][57];
  const int bh = blockIdx.x;           // b*56 + h
  const int h = bh % 56, b = bh / 56;
  const float* xp = x + (size_t)b * 256 * 3136 + h * 56;
  for (int f = threadIdx.x; f < 256 * 56; f += 256) {
    int c = f / 56, w = f % 56;
    t[c][w] = xp[(size_t)c * 3136 + w];
  }
  __syncthreads();
  f16* op = xpad + (((size_t)(b * 68) + h + 6) * 68 + 6) * 256;
  for (int g = threadIdx.x; g < 56 * 256; g += 256) {
    int w = g / 256, c = g % 256;
    op[(size_t)w * 256 + c] = (f16)t[c][w];
  }
}

// w1 (co,c,i,j) fp32 -> w1h[ij][co][c] fp16
__global__ void w1_transform(const float* __restrict__ w1, f16* __restrict__ w1h) {
  int idx = blockIdx.x * 256 + threadIdx.x;
  if (idx >= 49 * 128 * 256) return;
  int c = idx & 255;
  int rest = idx >> 8;
  int co = rest & 127;
  int ij = rest >> 7;
  w1h[idx] = (f16)w1[((size_t)co * 256 + c) * 49 + ij];
}

// ---------------- conv1 as implicit GEMM (MFMA fp16) ----------------
// M=50176 (positions), N=128 (co), K = 49 taps x 256 ch.
// 128x128 tile, 4 waves each 64x64 (4x4 frags of 16x16x32).
__global__ __launch_bounds__(256, 2) void conv1_gemm(
    const f16* __restrict__ xpad, const f16* __restrict__ w1h,
    const float* __restrict__ b1, float* __restrict__ kbuf) {
  __shared__ f16 Asm[128 * 32];
  __shared__ f16 Bsm[128 * 32];

  const int tid = threadIdx.x;
  const int wid = tid >> 6;
  const int lane = tid & 63;
  const int m0 = blockIdx.x * 128;

  // staging: each wave stages rows [wid*32, wid*32+32) in 2 issues of 16 rows
  const int rq0 = wid * 32 + (lane >> 2);
  const int rq1 = rq0 + 16;
  const int sub = (lane & 3) * 16;  // byte offset within a 64B (32ch) row slice

  auto pos_byte = [&](int r) -> int {
    int P = m0 + r;
    int bb = P / 3136;
    int rem = P - bb * 3136;
    int hh = rem / 56;
    int ww = rem - hh * 56;
    // padded NHWC: [b][hp][wp][256ch], orig (h,w) sits at padded (h+6,w+6);
    // tap (i,j) reads padded (h+2i, w+2j) -> base at (h,w), tap adds offset.
    return ((bb * 68 + hh) * 68 + ww) * 512;
  };
  const int pA0 = pos_byte(rq0) + sub;
  const int pA1 = pos_byte(rq1) + sub;
  const int pB0 = rq0 * 512 + sub;  // w1h row stride 256ch*2B
  const int pB1 = rq1 * 512 + sub;

  const char* xb = (const char*)xpad;
  const char* wb = (const char*)w1h;
  char* As = (char*)Asm;
  char* Bs = (char*)Bsm;
  const int ldsq = wid * 2048;

  const int wr = wid >> 1, wc = wid & 1;
  const int fo = (lane & 15) * 64 + (lane >> 4) * 16;
  const int aoff = wr * 4096 + fo;
  const int boff = wc * 4096 + fo;

  f32x4 acc[4][4] = {};

  for (int ij = 0; ij < 49; ++ij) {
    const int tap = ((ij / 7) * 136 + (ij % 7) * 2) * 512;  // (2i*68+2j)*512B
    const char* ga0 = xb + pA0 + tap;
    const char* ga1 = xb + pA1 + tap;
    const char* gb0 = wb + ij * 65536 + pB0;
    const char* gb1 = wb + ij * 65536 + pB1;
    for (int cc = 0; cc < 8; ++cc) {
      const int cb = cc * 64;  // 32 channels * 2B
      __syncthreads();
      GLDS16(ga0 + cb, As + ldsq);
      GLDS16(ga1 + cb, As + ldsq + 1024);
      GLDS16(gb0 + cb, Bs + ldsq);
      GLDS16(gb1 + cb, Bs + ldsq + 1024);
      __syncthreads();
      f16x8 af[4], bf[4];
#pragma unroll
      for (int m = 0; m < 4; ++m)
        af[m] = *(const f16x8*)(As + aoff + m * 1024);
#pragma unroll
      for (int n = 0; n < 4; ++n)
        bf[n] = *(const f16x8*)(Bs + boff + n * 1024);
#pragma unroll
      for (int m = 0; m < 4; ++m)
#pragma unroll
        for (int n = 0; n < 4; ++n)
          acc[m][n] = __builtin_amdgcn_mfma_f32_16x16x32_f16(
              af[m], bf[n], acc[m][n], 0, 0, 0);
    }
  }

  float bias[4];
#pragma unroll
  for (int n = 0; n < 4; ++n) bias[n] = b1[wc * 64 + n * 16 + (lane & 15)];

#pragma unroll
  for (int m = 0; m < 4; ++m) {
    const int row0 = m0 + wr * 64 + m * 16 + (lane >> 4) * 4;
#pragma unroll
    for (int n = 0; n < 4; ++n) {
      const int co = wc * 64 + n * 16 + (lane & 15);
#pragma unroll
      for (int r = 0; r < 4; ++r) {
        float v = acc[m][n][r] + bias[n];
        kbuf[(size_t)(row0 + r) * 128 + co] = v > 0.f ? v : 0.f;
      }
    }
  }
}

// ---------------- 1x1 conv + BN + relu + softmax(49) ----------------
// 64 threads / 64 positions per block, 784 blocks -> all CUs busy.
__global__ __launch_bounds__(64, 4) void conv2_bn_softmax(
    const float* __restrict__ kbuf, const float* __restrict__ w2,
    const float* __restrict__ b2, const float* __restrict__ gamma,
    const float* __restrict__ beta, const float* __restrict__ rmean,
    const float* __restrict__ rvar, float* __restrict__ attn) {
  __shared__ float w2s[49 * 128];
  __shared__ float outs[64 * 49];
  for (int i = threadIdx.x; i < 49 * 128; i += 64) w2s[i] = w2[i];
  __syncthreads();
  const int p = blockIdx.x * 64 + threadIdx.x;
  float acc[49];
#pragma unroll
  for (int o = 0; o < 49; ++o) acc[o] = 0.f;
  const float4* kp = (const float4*)(kbuf + (size_t)p * 128);
  for (int c4 = 0; c4 < 32; ++c4) {
    float4 kv = kp[c4];
#pragma unroll
    for (int o = 0; o < 49; ++o) {
      float4 wv = *(const float4*)(w2s + o * 128 + c4 * 4);
      acc[o] += kv.x * wv.x + kv.y * wv.y + kv.z * wv.z + kv.w * wv.w;
    }
  }
  float mx = -1e30f;
#pragma unroll
  for (int o = 0; o < 49; ++o) {
    float s = acc[o] + b2[o];
    float inv = gamma[o] * rsqrtf(rvar[o] + 1e-5f);
    s = (s - rmean[o]) * inv + beta[o];
    s = s > 0.f ? s : 0.f;
    acc[o] = s;
    mx = fmaxf(mx, s);
  }
  float sum = 0.f;
#pragma unroll
  for (int o = 0; o < 49; ++o) {
    float e = __expf(acc[o] - mx);
    acc[o] = e;
    sum += e;
  }
  const float rinv = 1.f / sum;
  float* orow = outs + threadIdx.x * 49;
#pragma unroll
  for (int o = 0; o < 49; ++o) orow[o] = acc[o] * rinv;
  __syncthreads();
  float* ab = attn + (size_t)blockIdx.x * (64 * 49);
  for (int i = threadIdx.x; i < 64 * 49; i += 64) ab[i] = outs[i];
}

// ---------------- attention-weighted aggregation (v2) ----------------
// Reads NHWC fp16 xpad directly (L2-resident per-batch slab). One wave
// handles 4 positions (w = q, q+2, q+4, q+6) which SHARE tap columns:
// 7 rows x 10 cols = 70 coalesced 512B loads instead of 196.
// Block = 14 waves = one full (b,h) row; epilogue transposes via LDS and
// writes NCHW coalesced. attn reads are wave-uniform -> scalar loads.
__global__ __launch_bounds__(896, 1) void aggregate2(
    const f16* __restrict__ xpad, const float* __restrict__ attn,
    float* __restrict__ out) {
  __shared__ float t[256][57];  // 58368 B
  const int bh = blockIdx.x;
  const int h = bh % 56, b = bh / 56;
  const int tid = threadIdx.x;
  const int wid = tid >> 6, lane = tid & 63;
  // 14 groups of 4 stride-2 positions: evens q=0,8,..,48; odds q=1,9,..,49
  const int q = (wid < 7) ? wid * 8 : (wid - 7) * 8 + 1;

  int ap[4];
#pragma unroll
  for (int p = 0; p < 4; ++p) ap[p] = ((b * 56 + h) * 56 + q + 2 * p) * 49;

  float acc[4][4] = {};
  // tap (i,j) for position (h,w) reads padded (h+2i, w+2j); here w=q+2p,
  // col = q + 2*tt with j = tt - p.
  const f16* rowb = xpad + ((size_t)(b * 68 + h) * 68 + q) * 256 + 4 * lane;

  for (int i = 0; i < 7; ++i) {
    const f16* rb = rowb + (size_t)(2 * i * 68) * 256;
#pragma unroll
    for (int tt = 0; tt < 10; ++tt) {
      f16x4 xv = *(const f16x4*)(rb + tt * 512);  // 2 cols per tt step
      float xf[4];
#pragma unroll
      for (int k = 0; k < 4; ++k) xf[k] = (float)xv[k];
#pragma unroll
      for (int p = 0; p < 4; ++p) {
        const int j = tt - p;
        if (j >= 0 && j < 7) {
          const float a = attn[ap[p] + i * 7 + j];
#pragma unroll
          for (int k = 0; k < 4; ++k) acc[p][k] = fmaf(a, xf[k], acc[p][k]);
        }
      }
    }
  }

  // stage to LDS, then coalesced NCHW write
#pragma unroll
  for (int p = 0; p < 4; ++p)
#pragma unroll
    for (int k = 0; k < 4; ++k) t[4 * lane + k][q + 2 * p] = acc[p][k];
  __syncthreads();
  float* ob = out + ((size_t)b * 256 * 56 + h) * 56;
  for (int f = tid; f < 256 * 56; f += 896) {
    int c = f / 56, w = f % 56;
    ob[(size_t)c * 3136 + w] = t[c][w];
  }
}

// ---------------- launch ----------------
extern "C" void kernel_launch(void* const* d_in, const int* in_sizes, int n_in,
                              void* d_out, int out_size, void* d_ws,
                              size_t ws_size, hipStream_t stream) {
  const float* x = (const float*)d_in[0];
  const float* w1 = (const float*)d_in[1];
  const float* b1 = (const float*)d_in[2];
  const float* w2 = (const float*)d_in[3];
  const float* b2 = (const float*)d_in[4];
  const float* gamma = (const float*)d_in[5];
  const float* beta = (const float*)d_in[6];
  const float* rmean = (const float*)d_in[7];
  const float* rvar = (const float*)d_in[8];
  float* out = (float*)d_out;

  char* ws = (char*)d_ws;
  f16* xpad = (f16*)ws;                      // 16*68*68*256*2 = 37,879,808 B
  f16* w1h = (f16*)(ws + 37879808);          // 49*128*256*2  =  3,211,264 B
  float* kbuf = (float*)(ws + 41091072);     // 50176*128*4   = 25,690,112 B
  float* attn = (float*)(ws + 66781184);     // 50176*49*4    =  9,834,496 B

  hipLaunchKernelGGL(zero_fill, dim3(2048), dim3(256), 0, stream, (uint4*)xpad,
                     2367488);
  hipLaunchKernelGGL(transpose_cast, dim3(896), dim3(256), 0, stream, x, xpad);
  hipLaunchKernelGGL(w1_transform, dim3(6272), dim3(256), 0, stream, w1, w1h);
  hipLaunchKernelGGL(conv1_gemm, dim3(392), dim3(256), 0, stream, xpad, w1h,
                     b1, kbuf);
  hipLaunchKernelGGL(conv2_bn_softmax, dim3(784), dim3(64), 0, stream, kbuf,
                     w2, b2, gamma, beta, rmean, rvar, attn);
  hipLaunchKernelGGL(aggregate2, dim3(896), dim3(896), 0, stream, x == 0 ? 0 : xpad, attn, out);
}